// Round 3
// baseline (9994.975 us; speedup 1.0000x reference)
//
#include <hip/hip_runtime.h>
#include <hip/hip_bf16.h>
#include <math.h>

#define NN 50000
#define NE 600000

// ---------------------------------------------------------------------------
// CSR build
// ---------------------------------------------------------------------------
__global__ __launch_bounds__(256) void hist_kernel(const int* __restrict__ dst,
                                                   int* __restrict__ deg, int E) {
    int e = blockIdx.x * 256 + threadIdx.x;
    if (e < E) atomicAdd(&deg[dst[e]], 1);
}

// single-block exclusive scan over deg[0..n) -> indptr[0..n], cursor[0..n)
__global__ __launch_bounds__(256) void scan_kernel(const int* __restrict__ deg,
                                                   int* __restrict__ indptr,
                                                   int* __restrict__ cursor, int n) {
    __shared__ int wsum[4];
    __shared__ int carry_s;
    const int tid = threadIdx.x, lane = tid & 63, wv = tid >> 6;
    if (tid == 0) carry_s = 0;
    __syncthreads();
    const int nceil = (n + 1023) & ~1023;
    for (int base = 0; base < nceil; base += 1024) {
        int i = base + tid * 4;
        int4 v = make_int4(0, 0, 0, 0);
        if (i + 3 < n) v = *(const int4*)(deg + i);
        else {
            if (i < n)     v.x = deg[i];
            if (i + 1 < n) v.y = deg[i + 1];
            if (i + 2 < n) v.z = deg[i + 2];
            if (i + 3 < n) v.w = deg[i + 3];
        }
        int tsum = v.x + v.y + v.z + v.w;
        int incl = tsum;
        #pragma unroll
        for (int off = 1; off < 64; off <<= 1) {
            int u = __shfl_up(incl, off);
            if (lane >= off) incl += u;
        }
        if (lane == 63) wsum[wv] = incl;
        __syncthreads();                       // A: wsum visible
        int wpre = 0;
        for (int w = 0; w < wv; ++w) wpre += wsum[w];
        int carry = carry_s;
        int start = carry + wpre + incl - tsum;
        if (i < n)     { indptr[i] = start;           cursor[i] = start; }
        int s1 = start + v.x;
        if (i + 1 < n) { indptr[i + 1] = s1;          cursor[i + 1] = s1; }
        int s2 = s1 + v.y;
        if (i + 2 < n) { indptr[i + 2] = s2;          cursor[i + 2] = s2; }
        int s3 = s2 + v.z;
        if (i + 3 < n) { indptr[i + 3] = s3;          cursor[i + 3] = s3; }
        __syncthreads();                       // B: all reads of wsum/carry done
        if (tid == 255) carry_s = carry + wpre + incl;
        __syncthreads();                       // C: carry update visible
    }
    if (tid == 0) indptr[n] = carry_s;
}

__global__ __launch_bounds__(256) void scatter_kernel(const int* __restrict__ src,
                                                      const int* __restrict__ dst,
                                                      int* __restrict__ cursor,
                                                      int* __restrict__ src_csr,
                                                      int* __restrict__ eid_csr, int E) {
    int e = blockIdx.x * 256 + threadIdx.x;
    if (e < E) {
        int d = dst[e];
        int slot = atomicAdd(&cursor[d], 1);
        src_csr[slot] = src[e];
        eid_csr[slot] = e;
    }
}

__global__ __launch_bounds__(256) void permute_ea(const int* __restrict__ eid_csr,
                                                  const float* __restrict__ ea,
                                                  float* __restrict__ ea_csr, int E) {
    int g = blockIdx.x * 256 + threadIdx.x;     // E*8 float4 elements
    if (g < E * 8) {
        int slot = g >> 3, q = g & 7;
        int eid = eid_csr[slot];
        ((float4*)ea_csr)[(size_t)slot * 8 + q] = ((const float4*)ea)[(size_t)eid * 8 + q];
    }
}

// ---------------------------------------------------------------------------
// fused QKV+skip GEMM: out[n, mat*128 + j] = X[n,:] @ W_mat + b_mat
// BM=64, BN=128, BK=32, 256 threads, thread tile 4x8
// ---------------------------------------------------------------------------
struct GemmArgs {
    const float* W[4];
    const float* b[4];
};

__global__ __launch_bounds__(256) void qkvsk_gemm(const float* __restrict__ X,
                                                  GemmArgs args,
                                                  float* __restrict__ out, int nrows) {
    __shared__ float Xs[64][33];
    __shared__ float Ws[32][132];
    const int mat = blockIdx.y;
    const float* __restrict__ W = args.W[mat];
    const float* __restrict__ bias = args.b[mat];
    const int n0 = blockIdx.x * 64;
    const int tid = threadIdx.x;
    const int tc = tid & 15;   // 8 cols each
    const int tr = tid >> 4;   // 4 rows each
    float acc[4][8];
    #pragma unroll
    for (int i = 0; i < 4; ++i)
        #pragma unroll
        for (int j = 0; j < 8; ++j) acc[i][j] = 0.f;

    for (int k0 = 0; k0 < 128; k0 += 32) {
        // load X tile 64x32 (512 float4)
        #pragma unroll
        for (int c = 0; c < 2; ++c) {
            int lin4 = tid + c * 256;
            int row = lin4 >> 3, kq = lin4 & 7;
            int gr = n0 + row;
            float4 v = make_float4(0.f, 0.f, 0.f, 0.f);
            if (gr < nrows) v = ((const float4*)X)[(size_t)gr * 32 + (k0 >> 2) + kq];
            Xs[row][kq * 4 + 0] = v.x; Xs[row][kq * 4 + 1] = v.y;
            Xs[row][kq * 4 + 2] = v.z; Xs[row][kq * 4 + 3] = v.w;
        }
        // load W tile 32x128 (1024 float4)
        #pragma unroll
        for (int c = 0; c < 4; ++c) {
            int lin4 = tid + c * 256;
            int row = lin4 >> 5, c4 = lin4 & 31;
            float4 v = ((const float4*)W)[(size_t)(k0 + row) * 32 + c4];
            Ws[row][c4 * 4 + 0] = v.x; Ws[row][c4 * 4 + 1] = v.y;
            Ws[row][c4 * 4 + 2] = v.z; Ws[row][c4 * 4 + 3] = v.w;
        }
        __syncthreads();
        for (int k = 0; k < 32; ++k) {
            float xf[4];
            #pragma unroll
            for (int i = 0; i < 4; ++i) xf[i] = Xs[tr * 4 + i][k];
            float4 w0 = *(const float4*)&Ws[k][tc * 8];
            float4 w1 = *(const float4*)&Ws[k][tc * 8 + 4];
            #pragma unroll
            for (int i = 0; i < 4; ++i) {
                acc[i][0] += xf[i] * w0.x; acc[i][1] += xf[i] * w0.y;
                acc[i][2] += xf[i] * w0.z; acc[i][3] += xf[i] * w0.w;
                acc[i][4] += xf[i] * w1.x; acc[i][5] += xf[i] * w1.y;
                acc[i][6] += xf[i] * w1.z; acc[i][7] += xf[i] * w1.w;
            }
        }
        __syncthreads();
    }
    float bv[8];
    #pragma unroll
    for (int j = 0; j < 8; ++j) bv[j] = bias[tc * 8 + j];
    #pragma unroll
    for (int i = 0; i < 4; ++i) {
        int gr = n0 + tr * 4 + i;
        if (gr < nrows) {
            float* orow = out + (size_t)gr * 512 + mat * 128 + tc * 8;
            float4 o0 = make_float4(acc[i][0] + bv[0], acc[i][1] + bv[1],
                                    acc[i][2] + bv[2], acc[i][3] + bv[3]);
            float4 o1 = make_float4(acc[i][4] + bv[4], acc[i][5] + bv[5],
                                    acc[i][6] + bv[6], acc[i][7] + bv[7]);
            *(float4*)orow = o0;
            *(float4*)(orow + 4) = o1;
        }
    }
}

// ---------------------------------------------------------------------------
// attention: one wave per destination node, online softmax over CSR edges.
// Algebraic reduction:  alpha = q.k[src] + sum_i ea[i]*t[h,i],
//   out = (sum a*v[src] + (sum a*ea) @ We) / sum a + skip.
// Lane l owns dims d0=2l,2l+1 (head h=l>>4) and ea slots i0=2(l&15),i0+1.
// ---------------------------------------------------------------------------
template <bool PERM>
__global__ __launch_bounds__(256) void attn_kernel(const float* __restrict__ qkvsk,
                                                   const int* __restrict__ indptr,
                                                   const int* __restrict__ src_csr,
                                                   const int* __restrict__ eid_csr,
                                                   const float* __restrict__ ea,
                                                   const float* __restrict__ We,
                                                   float* __restrict__ hout, int nnodes) {
    __shared__ float We_s[32 * 128];
    for (int i = threadIdx.x; i < 1024; i += 256)
        ((float4*)We_s)[i] = ((const float4*)We)[i];
    __syncthreads();

    const int lane = threadIdx.x & 63;
    const int n = blockIdx.x * 4 + (threadIdx.x >> 6);
    if (n >= nnodes) return;

    const int d0 = lane * 2;
    const int h = lane >> 4;
    const int i0 = (lane & 15) * 2;

    const float2* nrow = (const float2*)(qkvsk + (size_t)n * 512);
    const float2 q2 = nrow[lane];

    // prologue: t0,t1 = sum_c q[n,h,c] * We[i0(+1), h*32+c]
    float t0 = 0.f, t1 = 0.f;
    {
        const float4* qh = (const float4*)(qkvsk + (size_t)n * 512 + h * 32);
        #pragma unroll
        for (int c4 = 0; c4 < 8; ++c4) {
            float4 qv = qh[c4];
            int cb = h * 32 + c4 * 4;
            float4 w0 = *(const float4*)&We_s[i0 * 128 + cb];
            float4 w1 = *(const float4*)&We_s[(i0 + 1) * 128 + cb];
            t0 += qv.x * w0.x + qv.y * w0.y + qv.z * w0.z + qv.w * w0.w;
            t1 += qv.x * w1.x + qv.y * w1.y + qv.z * w1.z + qv.w * w1.w;
        }
    }

    float m = -INFINITY, ssum = 0.f;
    float accvx = 0.f, accvy = 0.f, accex = 0.f, accey = 0.f;
    const int s_end = indptr[n + 1];
    for (int s = indptr[n]; s < s_end; ++s) {
        int src = src_csr[s];
        size_t erow = PERM ? (size_t)s * 32 : (size_t)eid_csr[s] * 32;
        float2 ea2 = *(const float2*)(ea + erow + i0);
        const float2* srow = (const float2*)(qkvsk + (size_t)src * 512);
        float2 k2 = srow[64 + lane];
        float p = q2.x * k2.x + q2.y * k2.y + ea2.x * t0 + ea2.y * t1;
        p += __shfl_xor(p, 1);
        p += __shfl_xor(p, 2);
        p += __shfl_xor(p, 4);
        p += __shfl_xor(p, 8);
        float alpha = p * 0.17677669529663687f;   // 1/sqrt(32)
        float mnew = fmaxf(m, alpha);
        float sc = __expf(m - mnew);
        float a = __expf(alpha - mnew);
        m = mnew;
        ssum = ssum * sc + a;
        float2 v2 = srow[128 + lane];
        accvx = accvx * sc + a * v2.x;
        accvy = accvy * sc + a * v2.y;
        accex = accex * sc + a * ea2.x;
        accey = accey * sc + a * ea2.y;
    }

    // epilogue: contract acc_ea (distributed over the 16-lane head group) with We
    float e0 = 0.f, e1 = 0.f;
    const int gbase = lane & 48;
    #pragma unroll
    for (int ii = 0; ii < 16; ++ii) {
        float ax = __shfl(accex, gbase + ii);
        float ay = __shfl(accey, gbase + ii);
        int ia = ii * 2;
        float2 wA = *(const float2*)&We_s[ia * 128 + d0];
        float2 wB = *(const float2*)&We_s[(ia + 1) * 128 + d0];
        e0 += ax * wA.x + ay * wB.x;
        e1 += ax * wA.y + ay * wB.y;
    }

    float inv = (ssum > 0.f) ? 1.0f / ssum : 0.f;
    float2 sk2 = nrow[192 + lane];
    float o0 = (accvx + e0) * inv + sk2.x;
    float o1 = (accvy + e1) * inv + sk2.y;
    o0 = o0 > 0.f ? o0 : 0.01f * o0;
    o1 = o1 > 0.f ? o1 : 0.01f * o1;
    ((float2*)(hout + (size_t)n * 128))[lane] = make_float2(o0, o1);
}

// ---------------------------------------------------------------------------
// MLP: out = leaky(h @ W1 + b1) @ W2 + b2 ; half-wave (32 lanes) per node
// ---------------------------------------------------------------------------
__global__ __launch_bounds__(256) void mlp_kernel(const float* __restrict__ h,
                                                  const float* __restrict__ W1,
                                                  const float* __restrict__ b1,
                                                  const float* __restrict__ W2,
                                                  const float* __restrict__ b2,
                                                  float* __restrict__ out, int nnodes) {
    __shared__ float W1s[128 * 32];
    __shared__ float W2s[32 * 64];
    __shared__ float b1s[32], b2s[64];
    for (int i = threadIdx.x; i < 1024; i += 256)
        ((float4*)W1s)[i] = ((const float4*)W1)[i];
    for (int i = threadIdx.x; i < 512; i += 256)
        ((float4*)W2s)[i] = ((const float4*)W2)[i];
    if (threadIdx.x < 32) b1s[threadIdx.x] = b1[threadIdx.x];
    if (threadIdx.x < 64) b2s[threadIdx.x] = b2[threadIdx.x];
    __syncthreads();

    const int j = threadIdx.x & 31;
    const int n = blockIdx.x * 8 + (threadIdx.x >> 5);
    if (n >= nnodes) return;

    const float4* h4 = (const float4*)(h + (size_t)n * 128);
    float t = b1s[j];
    #pragma unroll
    for (int k4 = 0; k4 < 32; ++k4) {
        float4 hv = h4[k4];
        t += hv.x * W1s[(k4 * 4 + 0) * 32 + j];
        t += hv.y * W1s[(k4 * 4 + 1) * 32 + j];
        t += hv.z * W1s[(k4 * 4 + 2) * 32 + j];
        t += hv.w * W1s[(k4 * 4 + 3) * 32 + j];
    }
    t = t > 0.f ? t : 0.01f * t;

    float o0 = b2s[j], o1 = b2s[j + 32];
    const int base = threadIdx.x & 32;   // which half-wave
    #pragma unroll
    for (int c = 0; c < 32; ++c) {
        float tc = __shfl(t, base + c);
        o0 += tc * W2s[c * 64 + j];
        o1 += tc * W2s[c * 64 + j + 32];
    }
    out[(size_t)n * 64 + j] = o0;
    out[(size_t)n * 64 + j + 32] = o1;
}

// ---------------------------------------------------------------------------
extern "C" void kernel_launch(void* const* d_in, const int* in_sizes, int n_in,
                              void* d_out, int out_size, void* d_ws, size_t ws_size,
                              hipStream_t stream) {
    const float* x         = (const float*)d_in[0];
    const int*   edge_index= (const int*)d_in[2];
    const float* edge_attr = (const float*)d_in[3];
    const float* Wq0 = (const float*)d_in[5],  *Wk0 = (const float*)d_in[6];
    const float* Wv0 = (const float*)d_in[7],  *Wsk0= (const float*)d_in[8];
    const float* We0 = (const float*)d_in[9];
    const float* bq0 = (const float*)d_in[10], *bk0 = (const float*)d_in[11];
    const float* bv0 = (const float*)d_in[12], *bsk0= (const float*)d_in[13];
    const float* Wq1 = (const float*)d_in[14], *Wk1 = (const float*)d_in[15];
    const float* Wv1 = (const float*)d_in[16], *Wsk1= (const float*)d_in[17];
    const float* We1 = (const float*)d_in[18];
    const float* bq1 = (const float*)d_in[19], *bk1 = (const float*)d_in[20];
    const float* bv1 = (const float*)d_in[21], *bsk1= (const float*)d_in[22];
    const float* W1  = (const float*)d_in[23], *b1  = (const float*)d_in[24];
    const float* W2  = (const float*)d_in[25], *b2  = (const float*)d_in[26];

    const int N = in_sizes[0] / 128;
    const int E = in_sizes[2] / 2;
    const int* src = edge_index;
    const int* dst = edge_index + E;

    // workspace carve (256B aligned)
    char* p = (char*)d_ws;
    size_t used = 0;
    auto alloc = [&](size_t bytes) {
        void* r = p + used;
        used += (bytes + 255) & ~(size_t)255;
        return r;
    };
    int*   indptr  = (int*)alloc((size_t)(N + 1) * 4);
    int*   deg     = (int*)alloc((size_t)N * 4);
    int*   cursor  = (int*)alloc((size_t)N * 4);
    int*   src_csr = (int*)alloc((size_t)E * 4);
    int*   eid_csr = (int*)alloc((size_t)E * 4);
    float* qkvsk   = (float*)alloc((size_t)N * 512 * 4);
    float* h0      = (float*)alloc((size_t)N * 128 * 4);
    float* h1      = (float*)alloc((size_t)N * 128 * 4);
    float* ea_csr  = (float*)alloc((size_t)E * 32 * 4);
    const bool perm_ok = (used <= ws_size);

    // ---- CSR build ----
    hipMemsetAsync(deg, 0, (size_t)N * 4, stream);
    hist_kernel<<<(E + 255) / 256, 256, 0, stream>>>(dst, deg, E);
    scan_kernel<<<1, 256, 0, stream>>>(deg, indptr, cursor, N);
    scatter_kernel<<<(E + 255) / 256, 256, 0, stream>>>(src, dst, cursor, src_csr, eid_csr, E);
    if (perm_ok)
        permute_ea<<<((size_t)E * 8 + 255) / 256, 256, 0, stream>>>(eid_csr, edge_attr, ea_csr, E);

    dim3 ggrid((N + 63) / 64, 4);
    dim3 agrid((N + 3) / 4);

    // ---- layer 0 ----
    GemmArgs g0 = {{Wq0, Wk0, Wv0, Wsk0}, {bq0, bk0, bv0, bsk0}};
    qkvsk_gemm<<<ggrid, 256, 0, stream>>>(x, g0, qkvsk, N);
    if (perm_ok)
        attn_kernel<true><<<agrid, 256, 0, stream>>>(qkvsk, indptr, src_csr, eid_csr, ea_csr, We0, h0, N);
    else
        attn_kernel<false><<<agrid, 256, 0, stream>>>(qkvsk, indptr, src_csr, eid_csr, edge_attr, We0, h0, N);

    // ---- layer 1 ----
    GemmArgs g1 = {{Wq1, Wk1, Wv1, Wsk1}, {bq1, bk1, bv1, bsk1}};
    qkvsk_gemm<<<ggrid, 256, 0, stream>>>(h0, g1, qkvsk, N);
    if (perm_ok)
        attn_kernel<true><<<agrid, 256, 0, stream>>>(qkvsk, indptr, src_csr, eid_csr, ea_csr, We1, h1, N);
    else
        attn_kernel<false><<<agrid, 256, 0, stream>>>(qkvsk, indptr, src_csr, eid_csr, edge_attr, We1, h1, N);

    // ---- MLP head ----
    mlp_kernel<<<(N + 7) / 8, 256, 0, stream>>>(h1, W1, b1, W2, b2, (float*)d_out, N);
}

// Round 9
// 951.673 us; speedup vs baseline: 10.5025x; 10.5025x over previous
//
#include <hip/hip_runtime.h>
#include <hip/hip_bf16.h>
#include <math.h>

#define NN 50000
#define NE 600000

// ---------------------------------------------------------------------------
// CSR build
// ---------------------------------------------------------------------------
__global__ __launch_bounds__(256) void hist_kernel(const int* __restrict__ dst,
                                                   int* __restrict__ deg, int E) {
    int e = blockIdx.x * 256 + threadIdx.x;
    if (e < E) atomicAdd(&deg[dst[e]], 1);
}

// single-block exclusive scan over deg[0..n) -> indptr[0..n], cursor[0..n)
__global__ __launch_bounds__(256) void scan_kernel(const int* __restrict__ deg,
                                                   int* __restrict__ indptr,
                                                   int* __restrict__ cursor, int n) {
    __shared__ int wsum[4];
    __shared__ int carry_s;
    const int tid = threadIdx.x, lane = tid & 63, wv = tid >> 6;
    if (tid == 0) carry_s = 0;
    __syncthreads();
    const int nceil = (n + 1023) & ~1023;
    for (int base = 0; base < nceil; base += 1024) {
        int i = base + tid * 4;
        int4 v = make_int4(0, 0, 0, 0);
        if (i + 3 < n) v = *(const int4*)(deg + i);
        else {
            if (i < n)     v.x = deg[i];
            if (i + 1 < n) v.y = deg[i + 1];
            if (i + 2 < n) v.z = deg[i + 2];
            if (i + 3 < n) v.w = deg[i + 3];
        }
        int tsum = v.x + v.y + v.z + v.w;
        int incl = tsum;
        #pragma unroll
        for (int off = 1; off < 64; off <<= 1) {
            int u = __shfl_up(incl, off);
            if (lane >= off) incl += u;
        }
        if (lane == 63) wsum[wv] = incl;
        __syncthreads();                       // A: wsum visible
        int wpre = 0;
        for (int w = 0; w < wv; ++w) wpre += wsum[w];
        int carry = carry_s;
        int start = carry + wpre + incl - tsum;
        if (i < n)     { indptr[i] = start;           cursor[i] = start; }
        int s1 = start + v.x;
        if (i + 1 < n) { indptr[i + 1] = s1;          cursor[i + 1] = s1; }
        int s2 = s1 + v.y;
        if (i + 2 < n) { indptr[i + 2] = s2;          cursor[i + 2] = s2; }
        int s3 = s2 + v.z;
        if (i + 3 < n) { indptr[i + 3] = s3;          cursor[i + 3] = s3; }
        __syncthreads();                       // B: all reads of wsum/carry done
        if (tid == 255) carry_s = carry + wpre + incl;
        __syncthreads();                       // C: carry update visible
    }
    if (tid == 0) indptr[n] = carry_s;
}

__global__ __launch_bounds__(256) void scatter_kernel(const int* __restrict__ src,
                                                      const int* __restrict__ dst,
                                                      int* __restrict__ cursor,
                                                      int* __restrict__ src_csr,
                                                      int* __restrict__ eid_csr, int E) {
    int e = blockIdx.x * 256 + threadIdx.x;
    if (e < E) {
        int d = dst[e];
        int slot = atomicAdd(&cursor[d], 1);
        src_csr[slot] = src[e];
        eid_csr[slot] = e;
    }
}

__global__ __launch_bounds__(256) void permute_ea(const int* __restrict__ eid_csr,
                                                  const float* __restrict__ ea,
                                                  float* __restrict__ ea_csr, int E) {
    int g = blockIdx.x * 256 + threadIdx.x;     // E*8 float4 elements
    if (g < E * 8) {
        int slot = g >> 3, q = g & 7;
        int eid = eid_csr[slot];
        ((float4*)ea_csr)[(size_t)slot * 8 + q] = ((const float4*)ea)[(size_t)eid * 8 + q];
    }
}

// ---------------------------------------------------------------------------
// fused QKV+skip GEMM: out[n, mat*128 + j] = X[n,:] @ W_mat + b_mat
// BM=64, BN=128, BK=32, 256 threads, thread tile 4x8.
// mat selected by blockIdx.y via uniform switch (NOT a runtime-indexed array:
// that goes to scratch, rule #20). Unrolls bounded to stop the 256-VGPR
// spill blow-up seen in round 3 (8.9 GB scratch traffic/dispatch).
// ---------------------------------------------------------------------------
__global__ __launch_bounds__(256, 4) void qkvsk_gemm(const float* __restrict__ X,
        const float* __restrict__ Wq,  const float* __restrict__ bq,
        const float* __restrict__ Wk,  const float* __restrict__ bk,
        const float* __restrict__ Wv,  const float* __restrict__ bv,
        const float* __restrict__ Wsk, const float* __restrict__ bsk,
        float* __restrict__ out, int nrows) {
    __shared__ float XsT[32][68];    // [k][row], pad 68 (272B rows, 16B-aligned)
    __shared__ float Ws[32][132];
    const int mat = blockIdx.y;
    const float* __restrict__ W;
    const float* __restrict__ bias;
    switch (mat) {
        case 0:  W = Wq;  bias = bq;  break;
        case 1:  W = Wk;  bias = bk;  break;
        case 2:  W = Wv;  bias = bv;  break;
        default: W = Wsk; bias = bsk; break;
    }
    const int n0 = blockIdx.x * 64;
    const int tid = threadIdx.x;
    const int tc = tid & 15;   // 8 cols each
    const int tr = tid >> 4;   // 4 rows each
    float acc[4][8];
    #pragma unroll
    for (int i = 0; i < 4; ++i)
        #pragma unroll
        for (int j = 0; j < 8; ++j) acc[i][j] = 0.f;

    #pragma unroll 1
    for (int k0 = 0; k0 < 128; k0 += 32) {
        // load X tile 64 rows x 32 k, store TRANSPOSED [k][row]
        #pragma unroll
        for (int c = 0; c < 2; ++c) {
            int lin4 = tid + c * 256;
            int row = lin4 >> 3, kq = lin4 & 7;
            int gr = n0 + row;
            float4 v = make_float4(0.f, 0.f, 0.f, 0.f);
            if (gr < nrows) v = ((const float4*)X)[(size_t)gr * 32 + (k0 >> 2) + kq];
            XsT[kq * 4 + 0][row] = v.x;
            XsT[kq * 4 + 1][row] = v.y;
            XsT[kq * 4 + 2][row] = v.z;
            XsT[kq * 4 + 3][row] = v.w;
        }
        // load W tile 32x128 (1024 float4)
        #pragma unroll
        for (int c = 0; c < 4; ++c) {
            int lin4 = tid + c * 256;
            int row = lin4 >> 5, c4 = lin4 & 31;
            float4 v = ((const float4*)W)[(size_t)(k0 + row) * 32 + c4];
            Ws[row][c4 * 4 + 0] = v.x; Ws[row][c4 * 4 + 1] = v.y;
            Ws[row][c4 * 4 + 2] = v.z; Ws[row][c4 * 4 + 3] = v.w;
        }
        __syncthreads();
        #pragma unroll 8
        for (int k = 0; k < 32; ++k) {
            float4 xv = *(const float4*)&XsT[k][tr * 4];
            float4 w0 = *(const float4*)&Ws[k][tc * 8];
            float4 w1 = *(const float4*)&Ws[k][tc * 8 + 4];
            float xf[4] = {xv.x, xv.y, xv.z, xv.w};
            #pragma unroll
            for (int i = 0; i < 4; ++i) {
                acc[i][0] += xf[i] * w0.x; acc[i][1] += xf[i] * w0.y;
                acc[i][2] += xf[i] * w0.z; acc[i][3] += xf[i] * w0.w;
                acc[i][4] += xf[i] * w1.x; acc[i][5] += xf[i] * w1.y;
                acc[i][6] += xf[i] * w1.z; acc[i][7] += xf[i] * w1.w;
            }
        }
        __syncthreads();
    }
    float bfrag[8];
    #pragma unroll
    for (int j = 0; j < 8; ++j) bfrag[j] = bias[tc * 8 + j];
    #pragma unroll
    for (int i = 0; i < 4; ++i) {
        int gr = n0 + tr * 4 + i;
        if (gr < nrows) {
            float* orow = out + (size_t)gr * 512 + mat * 128 + tc * 8;
            float4 o0 = make_float4(acc[i][0] + bfrag[0], acc[i][1] + bfrag[1],
                                    acc[i][2] + bfrag[2], acc[i][3] + bfrag[3]);
            float4 o1 = make_float4(acc[i][4] + bfrag[4], acc[i][5] + bfrag[5],
                                    acc[i][6] + bfrag[6], acc[i][7] + bfrag[7]);
            *(float4*)orow = o0;
            *(float4*)(orow + 4) = o1;
        }
    }
}

// ---------------------------------------------------------------------------
// attention: one wave per destination node, online softmax over CSR edges.
// Algebraic reduction:  alpha = q.k[src] + sum_i ea[i]*t[h,i],
//   out = (sum a*v[src] + (sum a*ea) @ We) / sum a + skip.
// Lane l owns dims d0=2l,2l+1 (head h=l>>4) and ea slots i0=2(l&15),i0+1.
// ---------------------------------------------------------------------------
template <bool PERM>
__global__ __launch_bounds__(256) void attn_kernel(const float* __restrict__ qkvsk,
                                                   const int* __restrict__ indptr,
                                                   const int* __restrict__ src_csr,
                                                   const int* __restrict__ eid_csr,
                                                   const float* __restrict__ ea,
                                                   const float* __restrict__ We,
                                                   float* __restrict__ hout, int nnodes) {
    __shared__ float We_s[32 * 128];
    for (int i = threadIdx.x; i < 1024; i += 256)
        ((float4*)We_s)[i] = ((const float4*)We)[i];
    __syncthreads();

    const int lane = threadIdx.x & 63;
    const int n = blockIdx.x * 4 + (threadIdx.x >> 6);
    if (n >= nnodes) return;

    const int d0 = lane * 2;
    const int h = lane >> 4;
    const int i0 = (lane & 15) * 2;

    const float2* nrow = (const float2*)(qkvsk + (size_t)n * 512);
    const float2 q2 = nrow[lane];

    // prologue: t0,t1 = sum_c q[n,h,c] * We[i0(+1), h*32+c]
    float t0 = 0.f, t1 = 0.f;
    {
        const float4* qh = (const float4*)(qkvsk + (size_t)n * 512 + h * 32);
        #pragma unroll
        for (int c4 = 0; c4 < 8; ++c4) {
            float4 qv = qh[c4];
            int cb = h * 32 + c4 * 4;
            float4 w0 = *(const float4*)&We_s[i0 * 128 + cb];
            float4 w1 = *(const float4*)&We_s[(i0 + 1) * 128 + cb];
            t0 += qv.x * w0.x + qv.y * w0.y + qv.z * w0.z + qv.w * w0.w;
            t1 += qv.x * w1.x + qv.y * w1.y + qv.z * w1.z + qv.w * w1.w;
        }
    }

    float m = -INFINITY, ssum = 0.f;
    float accvx = 0.f, accvy = 0.f, accex = 0.f, accey = 0.f;
    const int s_end = indptr[n + 1];
    for (int s = indptr[n]; s < s_end; ++s) {
        int src = src_csr[s];
        size_t erow = PERM ? (size_t)s * 32 : (size_t)eid_csr[s] * 32;
        float2 ea2 = *(const float2*)(ea + erow + i0);
        const float2* srow = (const float2*)(qkvsk + (size_t)src * 512);
        float2 k2 = srow[64 + lane];
        float p = q2.x * k2.x + q2.y * k2.y + ea2.x * t0 + ea2.y * t1;
        p += __shfl_xor(p, 1);
        p += __shfl_xor(p, 2);
        p += __shfl_xor(p, 4);
        p += __shfl_xor(p, 8);
        float alpha = p * 0.17677669529663687f;   // 1/sqrt(32)
        float mnew = fmaxf(m, alpha);
        float sc = __expf(m - mnew);
        float a = __expf(alpha - mnew);
        m = mnew;
        ssum = ssum * sc + a;
        float2 v2 = srow[128 + lane];
        accvx = accvx * sc + a * v2.x;
        accvy = accvy * sc + a * v2.y;
        accex = accex * sc + a * ea2.x;
        accey = accey * sc + a * ea2.y;
    }

    // epilogue: contract acc_ea (distributed over the 16-lane head group) with We
    float e0 = 0.f, e1 = 0.f;
    const int gbase = lane & 48;
    #pragma unroll
    for (int ii = 0; ii < 16; ++ii) {
        float ax = __shfl(accex, gbase + ii);
        float ay = __shfl(accey, gbase + ii);
        int ia = ii * 2;
        float2 wA = *(const float2*)&We_s[ia * 128 + d0];
        float2 wB = *(const float2*)&We_s[(ia + 1) * 128 + d0];
        e0 += ax * wA.x + ay * wB.x;
        e1 += ax * wA.y + ay * wB.y;
    }

    float inv = (ssum > 0.f) ? 1.0f / ssum : 0.f;
    float2 sk2 = nrow[192 + lane];
    float o0 = (accvx + e0) * inv + sk2.x;
    float o1 = (accvy + e1) * inv + sk2.y;
    o0 = o0 > 0.f ? o0 : 0.01f * o0;
    o1 = o1 > 0.f ? o1 : 0.01f * o1;
    ((float2*)(hout + (size_t)n * 128))[lane] = make_float2(o0, o1);
}

// ---------------------------------------------------------------------------
// MLP: out = leaky(h @ W1 + b1) @ W2 + b2 ; half-wave (32 lanes) per node
// ---------------------------------------------------------------------------
__global__ __launch_bounds__(256) void mlp_kernel(const float* __restrict__ h,
                                                  const float* __restrict__ W1,
                                                  const float* __restrict__ b1,
                                                  const float* __restrict__ W2,
                                                  const float* __restrict__ b2,
                                                  float* __restrict__ out, int nnodes) {
    __shared__ float W1s[128 * 32];
    __shared__ float W2s[32 * 64];
    __shared__ float b1s[32], b2s[64];
    for (int i = threadIdx.x; i < 1024; i += 256)
        ((float4*)W1s)[i] = ((const float4*)W1)[i];
    for (int i = threadIdx.x; i < 512; i += 256)
        ((float4*)W2s)[i] = ((const float4*)W2)[i];
    if (threadIdx.x < 32) b1s[threadIdx.x] = b1[threadIdx.x];
    if (threadIdx.x < 64) b2s[threadIdx.x] = b2[threadIdx.x];
    __syncthreads();

    const int j = threadIdx.x & 31;
    const int n = blockIdx.x * 8 + (threadIdx.x >> 5);
    if (n >= nnodes) return;

    const float4* h4 = (const float4*)(h + (size_t)n * 128);
    float t = b1s[j];
    #pragma unroll
    for (int k4 = 0; k4 < 32; ++k4) {
        float4 hv = h4[k4];
        t += hv.x * W1s[(k4 * 4 + 0) * 32 + j];
        t += hv.y * W1s[(k4 * 4 + 1) * 32 + j];
        t += hv.z * W1s[(k4 * 4 + 2) * 32 + j];
        t += hv.w * W1s[(k4 * 4 + 3) * 32 + j];
    }
    t = t > 0.f ? t : 0.01f * t;

    float o0 = b2s[j], o1 = b2s[j + 32];
    const int base = threadIdx.x & 32;   // which half-wave
    #pragma unroll
    for (int c = 0; c < 32; ++c) {
        float tc = __shfl(t, base + c);
        o0 += tc * W2s[c * 64 + j];
        o1 += tc * W2s[c * 64 + j + 32];
    }
    out[(size_t)n * 64 + j] = o0;
    out[(size_t)n * 64 + j + 32] = o1;
}

// ---------------------------------------------------------------------------
extern "C" void kernel_launch(void* const* d_in, const int* in_sizes, int n_in,
                              void* d_out, int out_size, void* d_ws, size_t ws_size,
                              hipStream_t stream) {
    const float* x         = (const float*)d_in[0];
    const int*   edge_index= (const int*)d_in[2];
    const float* edge_attr = (const float*)d_in[3];
    const float* Wq0 = (const float*)d_in[5],  *Wk0 = (const float*)d_in[6];
    const float* Wv0 = (const float*)d_in[7],  *Wsk0= (const float*)d_in[8];
    const float* We0 = (const float*)d_in[9];
    const float* bq0 = (const float*)d_in[10], *bk0 = (const float*)d_in[11];
    const float* bv0 = (const float*)d_in[12], *bsk0= (const float*)d_in[13];
    const float* Wq1 = (const float*)d_in[14], *Wk1 = (const float*)d_in[15];
    const float* Wv1 = (const float*)d_in[16], *Wsk1= (const float*)d_in[17];
    const float* We1 = (const float*)d_in[18];
    const float* bq1 = (const float*)d_in[19], *bk1 = (const float*)d_in[20];
    const float* bv1 = (const float*)d_in[21], *bsk1= (const float*)d_in[22];
    const float* W1  = (const float*)d_in[23], *b1  = (const float*)d_in[24];
    const float* W2  = (const float*)d_in[25], *b2  = (const float*)d_in[26];

    const int N = in_sizes[0] / 128;
    const int E = in_sizes[2] / 2;
    const int* src = edge_index;
    const int* dst = edge_index + E;

    // workspace carve (256B aligned)
    char* p = (char*)d_ws;
    size_t used = 0;
    auto alloc = [&](size_t bytes) {
        void* r = p + used;
        used += (bytes + 255) & ~(size_t)255;
        return r;
    };
    int*   indptr  = (int*)alloc((size_t)(N + 1) * 4);
    int*   deg     = (int*)alloc((size_t)N * 4);
    int*   cursor  = (int*)alloc((size_t)N * 4);
    int*   src_csr = (int*)alloc((size_t)E * 4);
    int*   eid_csr = (int*)alloc((size_t)E * 4);
    float* qkvsk   = (float*)alloc((size_t)N * 512 * 4);
    float* h0      = (float*)alloc((size_t)N * 128 * 4);
    float* h1      = (float*)alloc((size_t)N * 128 * 4);
    float* ea_csr  = (float*)alloc((size_t)E * 32 * 4);
    const bool perm_ok = (used <= ws_size);

    // ---- CSR build ----
    (void)hipMemsetAsync(deg, 0, (size_t)N * 4, stream);
    hist_kernel<<<(E + 255) / 256, 256, 0, stream>>>(dst, deg, E);
    scan_kernel<<<1, 256, 0, stream>>>(deg, indptr, cursor, N);
    scatter_kernel<<<(E + 255) / 256, 256, 0, stream>>>(src, dst, cursor, src_csr, eid_csr, E);
    if (perm_ok)
        permute_ea<<<((size_t)E * 8 + 255) / 256, 256, 0, stream>>>(eid_csr, edge_attr, ea_csr, E);

    dim3 ggrid((N + 63) / 64, 4);
    dim3 agrid((N + 3) / 4);

    // ---- layer 0 ----
    qkvsk_gemm<<<ggrid, 256, 0, stream>>>(x, Wq0, bq0, Wk0, bk0, Wv0, bv0, Wsk0, bsk0, qkvsk, N);
    if (perm_ok)
        attn_kernel<true><<<agrid, 256, 0, stream>>>(qkvsk, indptr, src_csr, eid_csr, ea_csr, We0, h0, N);
    else
        attn_kernel<false><<<agrid, 256, 0, stream>>>(qkvsk, indptr, src_csr, eid_csr, edge_attr, We0, h0, N);

    // ---- layer 1 ----
    qkvsk_gemm<<<ggrid, 256, 0, stream>>>(h0, Wq1, bq1, Wk1, bk1, Wv1, bv1, Wsk1, bsk1, qkvsk, N);
    if (perm_ok)
        attn_kernel<true><<<agrid, 256, 0, stream>>>(qkvsk, indptr, src_csr, eid_csr, ea_csr, We1, h1, N);
    else
        attn_kernel<false><<<agrid, 256, 0, stream>>>(qkvsk, indptr, src_csr, eid_csr, edge_attr, We1, h1, N);

    // ---- MLP head ----
    mlp_kernel<<<(N + 7) / 8, 256, 0, stream>>>(h1, W1, b1, W2, b2, (float*)d_out, N);
}

// Round 14
// 817.804 us; speedup vs baseline: 12.2217x; 1.1637x over previous
//
#include <hip/hip_runtime.h>
#include <hip/hip_bf16.h>
#include <math.h>

// ---------------------------------------------------------------------------
// CSR build
// ---------------------------------------------------------------------------
__global__ __launch_bounds__(256) void hist_kernel(const int* __restrict__ dst,
                                                   int* __restrict__ deg, int E) {
    int e = blockIdx.x * 256 + threadIdx.x;
    if (e < E) atomicAdd(&deg[dst[e]], 1);
}

// single-block exclusive scan over deg[0..n) -> indptr[0..n], cursor[0..n)
__global__ __launch_bounds__(256) void scan_kernel(const int* __restrict__ deg,
                                                   int* __restrict__ indptr,
                                                   int* __restrict__ cursor, int n) {
    __shared__ int wsum[4];
    __shared__ int carry_s;
    const int tid = threadIdx.x, lane = tid & 63, wv = tid >> 6;
    if (tid == 0) carry_s = 0;
    __syncthreads();
    const int nceil = (n + 1023) & ~1023;
    for (int base = 0; base < nceil; base += 1024) {
        int i = base + tid * 4;
        int4 v = make_int4(0, 0, 0, 0);
        if (i + 3 < n) v = *(const int4*)(deg + i);
        else {
            if (i < n)     v.x = deg[i];
            if (i + 1 < n) v.y = deg[i + 1];
            if (i + 2 < n) v.z = deg[i + 2];
            if (i + 3 < n) v.w = deg[i + 3];
        }
        int tsum = v.x + v.y + v.z + v.w;
        int incl = tsum;
        #pragma unroll
        for (int off = 1; off < 64; off <<= 1) {
            int u = __shfl_up(incl, off);
            if (lane >= off) incl += u;
        }
        if (lane == 63) wsum[wv] = incl;
        __syncthreads();                       // A: wsum visible
        int wpre = 0;
        for (int w = 0; w < wv; ++w) wpre += wsum[w];
        int carry = carry_s;
        int start = carry + wpre + incl - tsum;
        if (i < n)     { indptr[i] = start;           cursor[i] = start; }
        int s1 = start + v.x;
        if (i + 1 < n) { indptr[i + 1] = s1;          cursor[i + 1] = s1; }
        int s2 = s1 + v.y;
        if (i + 2 < n) { indptr[i + 2] = s2;          cursor[i + 2] = s2; }
        int s3 = s2 + v.z;
        if (i + 3 < n) { indptr[i + 3] = s3;          cursor[i + 3] = s3; }
        __syncthreads();                       // B: all reads of wsum/carry done
        if (tid == 255) carry_s = carry + wpre + incl;
        __syncthreads();                       // C: carry update visible
    }
    if (tid == 0) indptr[n] = carry_s;
}

__global__ __launch_bounds__(256) void scatter_kernel(const int* __restrict__ src,
                                                      const int* __restrict__ dst,
                                                      int* __restrict__ cursor,
                                                      int* __restrict__ src_csr,
                                                      int* __restrict__ eid_csr, int E) {
    int e = blockIdx.x * 256 + threadIdx.x;
    if (e < E) {
        int d = dst[e];
        int slot = atomicAdd(&cursor[d], 1);
        src_csr[slot] = src[e];
        eid_csr[slot] = e;
    }
}

__global__ __launch_bounds__(256) void permute_ea(const int* __restrict__ eid_csr,
                                                  const float* __restrict__ ea,
                                                  float* __restrict__ ea_csr, int E) {
    int g = blockIdx.x * 256 + threadIdx.x;     // E*8 float4 elements
    if (g < E * 8) {
        int slot = g >> 3, q = g & 7;
        int eid = eid_csr[slot];
        ((float4*)ea_csr)[(size_t)slot * 8 + q] = ((const float4*)ea)[(size_t)eid * 8 + q];
    }
}

// ---------------------------------------------------------------------------
// fused QKV+skip GEMM.  Output split into two tables (round 10):
//   qsk[N,256] = [q | skip]   (read per-node, streamed in attn)
//   kv [N,256] = [k | v]      (gathered by src in attn; 51 MB working set)
// BM=64, BN=128, BK=32, 256 threads, thread tile 4x8.
// mat via uniform switch (rule #20); bounded unrolls (round-3 spill lesson).
// ---------------------------------------------------------------------------
__global__ __launch_bounds__(256, 4) void qkvsk_gemm(const float* __restrict__ X,
        const float* __restrict__ Wq,  const float* __restrict__ bq,
        const float* __restrict__ Wk,  const float* __restrict__ bk,
        const float* __restrict__ Wv,  const float* __restrict__ bv,
        const float* __restrict__ Wsk, const float* __restrict__ bsk,
        float* __restrict__ qsk, float* __restrict__ kv, int nrows) {
    __shared__ float XsT[32][68];    // [k][row], pad 68 (272B rows, 16B-aligned)
    __shared__ float Ws[32][132];
    const int mat = blockIdx.y;
    const float* __restrict__ W;
    const float* __restrict__ bias;
    float* __restrict__ out;
    int col;
    switch (mat) {
        case 0:  W = Wq;  bias = bq;  out = qsk; col = 0;   break;
        case 1:  W = Wk;  bias = bk;  out = kv;  col = 0;   break;
        case 2:  W = Wv;  bias = bv;  out = kv;  col = 128; break;
        default: W = Wsk; bias = bsk; out = qsk; col = 128; break;
    }
    const int n0 = blockIdx.x * 64;
    const int tid = threadIdx.x;
    const int tc = tid & 15;   // 8 cols each
    const int tr = tid >> 4;   // 4 rows each
    float acc[4][8];
    #pragma unroll
    for (int i = 0; i < 4; ++i)
        #pragma unroll
        for (int j = 0; j < 8; ++j) acc[i][j] = 0.f;

    #pragma unroll 1
    for (int k0 = 0; k0 < 128; k0 += 32) {
        // load X tile 64 rows x 32 k, store TRANSPOSED [k][row]
        #pragma unroll
        for (int c = 0; c < 2; ++c) {
            int lin4 = tid + c * 256;
            int row = lin4 >> 3, kq = lin4 & 7;
            int gr = n0 + row;
            float4 v = make_float4(0.f, 0.f, 0.f, 0.f);
            if (gr < nrows) v = ((const float4*)X)[(size_t)gr * 32 + (k0 >> 2) + kq];
            XsT[kq * 4 + 0][row] = v.x;
            XsT[kq * 4 + 1][row] = v.y;
            XsT[kq * 4 + 2][row] = v.z;
            XsT[kq * 4 + 3][row] = v.w;
        }
        // load W tile 32x128 (1024 float4)
        #pragma unroll
        for (int c = 0; c < 4; ++c) {
            int lin4 = tid + c * 256;
            int row = lin4 >> 5, c4 = lin4 & 31;
            float4 v = ((const float4*)W)[(size_t)(k0 + row) * 32 + c4];
            Ws[row][c4 * 4 + 0] = v.x; Ws[row][c4 * 4 + 1] = v.y;
            Ws[row][c4 * 4 + 2] = v.z; Ws[row][c4 * 4 + 3] = v.w;
        }
        __syncthreads();
        #pragma unroll 8
        for (int k = 0; k < 32; ++k) {
            float4 xv = *(const float4*)&XsT[k][tr * 4];
            float4 w0 = *(const float4*)&Ws[k][tc * 8];
            float4 w1 = *(const float4*)&Ws[k][tc * 8 + 4];
            float xf[4] = {xv.x, xv.y, xv.z, xv.w};
            #pragma unroll
            for (int i = 0; i < 4; ++i) {
                acc[i][0] += xf[i] * w0.x; acc[i][1] += xf[i] * w0.y;
                acc[i][2] += xf[i] * w0.z; acc[i][3] += xf[i] * w0.w;
                acc[i][4] += xf[i] * w1.x; acc[i][5] += xf[i] * w1.y;
                acc[i][6] += xf[i] * w1.z; acc[i][7] += xf[i] * w1.w;
            }
        }
        __syncthreads();
    }
    float bfrag[8];
    #pragma unroll
    for (int j = 0; j < 8; ++j) bfrag[j] = bias[tc * 8 + j];
    #pragma unroll
    for (int i = 0; i < 4; ++i) {
        int gr = n0 + tr * 4 + i;
        if (gr < nrows) {
            float* orow = out + (size_t)gr * 256 + col + tc * 8;
            float4 o0 = make_float4(acc[i][0] + bfrag[0], acc[i][1] + bfrag[1],
                                    acc[i][2] + bfrag[2], acc[i][3] + bfrag[3]);
            float4 o1 = make_float4(acc[i][4] + bfrag[4], acc[i][5] + bfrag[5],
                                    acc[i][6] + bfrag[6], acc[i][7] + bfrag[7]);
            *(float4*)orow = o0;
            *(float4*)(orow + 4) = o1;
        }
    }
}

// ---------------------------------------------------------------------------
// attention: one wave per destination node, online softmax over CSR edges.
//   alpha = q.k[src] + sum_i ea[i]*t[h,i];  out = (sum a*v + (sum a*ea)@We)/sum a + skip
// Round 10: 2-way edge ILP (dual chains A/B, merged at end) to hide gather
// latency; kv split table (51 MB gather set); We_s padded to 132 (bank fix).
// Lane l owns dims d0=2l,2l+1 (head h=l>>4) and ea slots i0=2(l&15),i0+1.
// ---------------------------------------------------------------------------
template <bool PERM>
__global__ __launch_bounds__(256) void attn_kernel(const float* __restrict__ qsk,
                                                   const float* __restrict__ kv,
                                                   const int* __restrict__ indptr,
                                                   const int* __restrict__ src_csr,
                                                   const int* __restrict__ eid_csr,
                                                   const float* __restrict__ ea,
                                                   const float* __restrict__ We,
                                                   float* __restrict__ hout, int nnodes) {
    __shared__ float We_s[32 * 132];           // rows padded 128->132 (4-way max)
    for (int i4 = threadIdx.x; i4 < 1024; i4 += 256) {
        int r = i4 >> 5, c4 = i4 & 31;
        float4 v = ((const float4*)We)[i4];
        *((float4*)(We_s + r * 132 + c4 * 4)) = v;
    }
    __syncthreads();

    const int lane = threadIdx.x & 63;
    const int n = blockIdx.x * 4 + (threadIdx.x >> 6);
    if (n >= nnodes) return;

    const int d0 = lane * 2;
    const int h = lane >> 4;
    const int i0 = (lane & 15) * 2;

    const float2* nrow = (const float2*)(qsk + (size_t)n * 256);
    const float2 q2 = nrow[lane];

    // prologue: t0,t1 = sum_c q[n,h,c] * We[i0(+1), h*32+c]
    float t0 = 0.f, t1 = 0.f;
    {
        const float4* qh = (const float4*)(qsk + (size_t)n * 256 + h * 32);
        #pragma unroll
        for (int c4 = 0; c4 < 8; ++c4) {
            float4 qv = qh[c4];
            int cb = h * 32 + c4 * 4;
            float4 w0 = *(const float4*)&We_s[i0 * 132 + cb];
            float4 w1 = *(const float4*)&We_s[(i0 + 1) * 132 + cb];
            t0 += qv.x * w0.x + qv.y * w0.y + qv.z * w0.z + qv.w * w0.w;
            t1 += qv.x * w1.x + qv.y * w1.y + qv.z * w1.z + qv.w * w1.w;
        }
    }

    const float scale = 0.17677669529663687f;   // 1/sqrt(32)
    // dual independent online-softmax chains (A = even slots, B = odd slots)
    float mA = -INFINITY, ssA = 0.f, avxA = 0.f, avyA = 0.f, aexA = 0.f, aeyA = 0.f;
    float mB = -INFINITY, ssB = 0.f, avxB = 0.f, avyB = 0.f, aexB = 0.f, aeyB = 0.f;

    int s = indptr[n];
    const int s_end = indptr[n + 1];
    #pragma unroll 1
    for (; s + 1 < s_end; s += 2) {
        int srcA = src_csr[s];
        int srcB = src_csr[s + 1];
        size_t erowA = PERM ? (size_t)s * 32       : (size_t)eid_csr[s] * 32;
        size_t erowB = PERM ? (size_t)(s + 1) * 32 : (size_t)eid_csr[s + 1] * 32;
        float2 eaA = *(const float2*)(ea + erowA + i0);
        float2 eaB = *(const float2*)(ea + erowB + i0);
        const float2* rowA = (const float2*)(kv + (size_t)srcA * 256);
        const float2* rowB = (const float2*)(kv + (size_t)srcB * 256);
        float2 kA = rowA[lane];
        float2 kB = rowB[lane];
        float2 vA = rowA[64 + lane];
        float2 vB = rowB[64 + lane];
        float pA = q2.x * kA.x + q2.y * kA.y + eaA.x * t0 + eaA.y * t1;
        float pB = q2.x * kB.x + q2.y * kB.y + eaB.x * t0 + eaB.y * t1;
        pA += __shfl_xor(pA, 1);  pB += __shfl_xor(pB, 1);
        pA += __shfl_xor(pA, 2);  pB += __shfl_xor(pB, 2);
        pA += __shfl_xor(pA, 4);  pB += __shfl_xor(pB, 4);
        pA += __shfl_xor(pA, 8);  pB += __shfl_xor(pB, 8);
        float alA = pA * scale;
        float alB = pB * scale;
        // chain A update
        {
            float mn = fmaxf(mA, alA);
            float sc = __expf(mA - mn);
            float a  = __expf(alA - mn);
            mA = mn;
            ssA  = ssA  * sc + a;
            avxA = avxA * sc + a * vA.x;
            avyA = avyA * sc + a * vA.y;
            aexA = aexA * sc + a * eaA.x;
            aeyA = aeyA * sc + a * eaA.y;
        }
        // chain B update
        {
            float mn = fmaxf(mB, alB);
            float sc = __expf(mB - mn);
            float a  = __expf(alB - mn);
            mB = mn;
            ssB  = ssB  * sc + a;
            avxB = avxB * sc + a * vB.x;
            avyB = avyB * sc + a * vB.y;
            aexB = aexB * sc + a * eaB.x;
            aeyB = aeyB * sc + a * eaB.y;
        }
    }
    if (s < s_end) {   // odd tail -> chain A
        int srcA = src_csr[s];
        size_t erowA = PERM ? (size_t)s * 32 : (size_t)eid_csr[s] * 32;
        float2 eaA = *(const float2*)(ea + erowA + i0);
        const float2* rowA = (const float2*)(kv + (size_t)srcA * 256);
        float2 kA = rowA[lane];
        float2 vA = rowA[64 + lane];
        float pA = q2.x * kA.x + q2.y * kA.y + eaA.x * t0 + eaA.y * t1;
        pA += __shfl_xor(pA, 1);
        pA += __shfl_xor(pA, 2);
        pA += __shfl_xor(pA, 4);
        pA += __shfl_xor(pA, 8);
        float alA = pA * scale;
        float mn = fmaxf(mA, alA);
        float sc = __expf(mA - mn);
        float a  = __expf(alA - mn);
        mA = mn;
        ssA  = ssA  * sc + a;
        avxA = avxA * sc + a * vA.x;
        avyA = avyA * sc + a * vA.y;
        aexA = aexA * sc + a * eaA.x;
        aeyA = aeyA * sc + a * eaA.y;
    }

    // merge chains (guard empty chains: exp(-inf - -inf) would be NaN)
    const float mm = fmaxf(mA, mB);
    const float scA = (mA > -INFINITY) ? __expf(mA - mm) : 0.f;
    const float scB = (mB > -INFINITY) ? __expf(mB - mm) : 0.f;
    const float ssum  = ssA * scA + ssB * scB;
    const float accvx = avxA * scA + avxB * scB;
    const float accvy = avyA * scA + avyB * scB;
    const float accex = aexA * scA + aexB * scB;
    const float accey = aeyA * scA + aeyB * scB;

    // epilogue: contract acc_ea (distributed over the 16-lane head group) with We
    float e0 = 0.f, e1 = 0.f;
    const int gbase = lane & 48;
    #pragma unroll
    for (int ii = 0; ii < 16; ++ii) {
        float ax = __shfl(accex, gbase + ii);
        float ay = __shfl(accey, gbase + ii);
        int ia = ii * 2;
        float2 wA = *(const float2*)&We_s[ia * 132 + d0];
        float2 wB = *(const float2*)&We_s[(ia + 1) * 132 + d0];
        e0 += ax * wA.x + ay * wB.x;
        e1 += ax * wA.y + ay * wB.y;
    }

    float inv = (ssum > 0.f) ? 1.0f / ssum : 0.f;
    float2 sk2 = nrow[64 + lane];
    float o0 = (accvx + e0) * inv + sk2.x;
    float o1 = (accvy + e1) * inv + sk2.y;
    o0 = o0 > 0.f ? o0 : 0.01f * o0;
    o1 = o1 > 0.f ? o1 : 0.01f * o1;
    ((float2*)(hout + (size_t)n * 128))[lane] = make_float2(o0, o1);
}

// ---------------------------------------------------------------------------
// MLP: out = leaky(h @ W1 + b1) @ W2 + b2 ; half-wave (32 lanes) per node
// ---------------------------------------------------------------------------
__global__ __launch_bounds__(256) void mlp_kernel(const float* __restrict__ h,
                                                  const float* __restrict__ W1,
                                                  const float* __restrict__ b1,
                                                  const float* __restrict__ W2,
                                                  const float* __restrict__ b2,
                                                  float* __restrict__ out, int nnodes) {
    __shared__ float W1s[128 * 32];
    __shared__ float W2s[32 * 64];
    __shared__ float b1s[32], b2s[64];
    for (int i = threadIdx.x; i < 1024; i += 256)
        ((float4*)W1s)[i] = ((const float4*)W1)[i];
    for (int i = threadIdx.x; i < 512; i += 256)
        ((float4*)W2s)[i] = ((const float4*)W2)[i];
    if (threadIdx.x < 32) b1s[threadIdx.x] = b1[threadIdx.x];
    if (threadIdx.x < 64) b2s[threadIdx.x] = b2[threadIdx.x];
    __syncthreads();

    const int j = threadIdx.x & 31;
    const int n = blockIdx.x * 8 + (threadIdx.x >> 5);
    if (n >= nnodes) return;

    const float4* h4 = (const float4*)(h + (size_t)n * 128);
    float t = b1s[j];
    #pragma unroll
    for (int k4 = 0; k4 < 32; ++k4) {
        float4 hv = h4[k4];
        t += hv.x * W1s[(k4 * 4 + 0) * 32 + j];
        t += hv.y * W1s[(k4 * 4 + 1) * 32 + j];
        t += hv.z * W1s[(k4 * 4 + 2) * 32 + j];
        t += hv.w * W1s[(k4 * 4 + 3) * 32 + j];
    }
    t = t > 0.f ? t : 0.01f * t;

    float o0 = b2s[j], o1 = b2s[j + 32];
    const int base = threadIdx.x & 32;   // which half-wave
    #pragma unroll
    for (int c = 0; c < 32; ++c) {
        float tc = __shfl(t, base + c);
        o0 += tc * W2s[c * 64 + j];
        o1 += tc * W2s[c * 64 + j + 32];
    }
    out[(size_t)n * 64 + j] = o0;
    out[(size_t)n * 64 + j + 32] = o1;
}

// ---------------------------------------------------------------------------
extern "C" void kernel_launch(void* const* d_in, const int* in_sizes, int n_in,
                              void* d_out, int out_size, void* d_ws, size_t ws_size,
                              hipStream_t stream) {
    const float* x         = (const float*)d_in[0];
    const int*   edge_index= (const int*)d_in[2];
    const float* edge_attr = (const float*)d_in[3];
    const float* Wq0 = (const float*)d_in[5],  *Wk0 = (const float*)d_in[6];
    const float* Wv0 = (const float*)d_in[7],  *Wsk0= (const float*)d_in[8];
    const float* We0 = (const float*)d_in[9];
    const float* bq0 = (const float*)d_in[10], *bk0 = (const float*)d_in[11];
    const float* bv0 = (const float*)d_in[12], *bsk0= (const float*)d_in[13];
    const float* Wq1 = (const float*)d_in[14], *Wk1 = (const float*)d_in[15];
    const float* Wv1 = (const float*)d_in[16], *Wsk1= (const float*)d_in[17];
    const float* We1 = (const float*)d_in[18];
    const float* bq1 = (const float*)d_in[19], *bk1 = (const float*)d_in[20];
    const float* bv1 = (const float*)d_in[21], *bsk1= (const float*)d_in[22];
    const float* W1  = (const float*)d_in[23], *b1  = (const float*)d_in[24];
    const float* W2  = (const float*)d_in[25], *b2  = (const float*)d_in[26];

    const int N = in_sizes[0] / 128;
    const int E = in_sizes[2] / 2;
    const int* src = edge_index;
    const int* dst = edge_index + E;

    // workspace carve (256B aligned)
    char* p = (char*)d_ws;
    size_t used = 0;
    auto alloc = [&](size_t bytes) {
        void* r = p + used;
        used += (bytes + 255) & ~(size_t)255;
        return r;
    };
    int*   indptr  = (int*)alloc((size_t)(N + 1) * 4);
    int*   deg     = (int*)alloc((size_t)N * 4);
    int*   cursor  = (int*)alloc((size_t)N * 4);
    int*   src_csr = (int*)alloc((size_t)E * 4);
    int*   eid_csr = (int*)alloc((size_t)E * 4);
    float* qsk     = (float*)alloc((size_t)N * 256 * 4);
    float* kvt     = (float*)alloc((size_t)N * 256 * 4);
    float* h0      = (float*)alloc((size_t)N * 128 * 4);
    float* h1      = (float*)alloc((size_t)N * 128 * 4);
    float* ea_csr  = (float*)alloc((size_t)E * 32 * 4);
    const bool perm_ok = (used <= ws_size);

    // ---- CSR build ----
    (void)hipMemsetAsync(deg, 0, (size_t)N * 4, stream);
    hist_kernel<<<(E + 255) / 256, 256, 0, stream>>>(dst, deg, E);
    scan_kernel<<<1, 256, 0, stream>>>(deg, indptr, cursor, N);
    scatter_kernel<<<(E + 255) / 256, 256, 0, stream>>>(src, dst, cursor, src_csr, eid_csr, E);
    if (perm_ok)
        permute_ea<<<((size_t)E * 8 + 255) / 256, 256, 0, stream>>>(eid_csr, edge_attr, ea_csr, E);

    dim3 ggrid((N + 63) / 64, 4);
    dim3 agrid((N + 3) / 4);

    // ---- layer 0 ----
    qkvsk_gemm<<<ggrid, 256, 0, stream>>>(x, Wq0, bq0, Wk0, bk0, Wv0, bv0, Wsk0, bsk0, qsk, kvt, N);
    if (perm_ok)
        attn_kernel<true><<<agrid, 256, 0, stream>>>(qsk, kvt, indptr, src_csr, eid_csr, ea_csr, We0, h0, N);
    else
        attn_kernel<false><<<agrid, 256, 0, stream>>>(qsk, kvt, indptr, src_csr, eid_csr, edge_attr, We0, h0, N);

    // ---- layer 1 ----
    qkvsk_gemm<<<ggrid, 256, 0, stream>>>(h0, Wq1, bq1, Wk1, bk1, Wv1, bv1, Wsk1, bsk1, qsk, kvt, N);
    if (perm_ok)
        attn_kernel<true><<<agrid, 256, 0, stream>>>(qsk, kvt, indptr, src_csr, eid_csr, ea_csr, We1, h1, N);
    else
        attn_kernel<false><<<agrid, 256, 0, stream>>>(qsk, kvt, indptr, src_csr, eid_csr, edge_attr, We1, h1, N);

    // ---- MLP head ----
    mlp_kernel<<<(N + 7) / 8, 256, 0, stream>>>(h1, W1, b1, W2, b2, (float*)d_out, N);
}